// Round 11
// baseline (393.959 us; speedup 1.0000x reference)
//
#include <hip/hip_runtime.h>
#include <stdint.h>

typedef float f32x4 __attribute__((ext_vector_type(4)));
typedef short bf16x8 __attribute__((ext_vector_type(8)));
typedef float fragc __attribute__((ext_vector_type(4)));
typedef uint32_t u32x4 __attribute__((ext_vector_type(4)));

__device__ __forceinline__ uint32_t pk2(float lo, float hi) {
  // (bf16(lo) | bf16(hi)<<16) via one v_perm_b32 (truncating)
  return __builtin_amdgcn_perm(__float_as_uint(hi), __float_as_uint(lo), 0x07060302u);
}

#define WS_B_OFF 67108864ull  // B'' at ws + 64 MiB

// ---------- Pass 1: [1024 s][512 r][64 h] f32 -> bf16 ws[kq 128][rw 8][h 64][r 64][16B]
// No LDS: lanes {c, c+16, c+32, c+48} of one store-instr write r=0..3 of the SAME
// 64B line (line-complete). Reads 1KB contiguous per wave-instr, NT (single-touch).
// Load order: all window-1 loads then window-2, so o1 stores start at vmcnt(8).
__global__ __launch_bounds__(512) void pack_kernel(const float* __restrict__ Ag,
                                                   const float* __restrict__ Bg,
                                                   uint8_t* __restrict__ ws) {
  const int bid  = blockIdx.x;
  const int rw   = bid & 7;
  const int kq   = (bid >> 3) & 127;
  const int side = bid >> 10;
  const int t    = threadIdx.x;

  const f32x4* S4 = (const f32x4*)(side ? Bg : Ag);
  uint8_t* dst = ws + (side ? WS_B_OFF : 0ull);

  const int base = rw * 1024 + t;
  f32x4 r1[8], r2[8];
#pragma unroll
  for (int e = 0; e < 8; ++e)
    r1[e] = __builtin_nontemporal_load(&S4[(size_t)(kq * 8 + e) * 8192 + base]);
#pragma unroll
  for (int e = 0; e < 8; ++e)
    r2[e] = __builtin_nontemporal_load(&S4[(size_t)(kq * 8 + e) * 8192 + base + 512]);

  const int hq = t & 15;
  const int ra = t >> 4;  // 0..31
#pragma unroll
  for (int e = 0; e < 4; ++e) {  // window-1 stores: only need r1 (vmcnt(8))
    const int h = hq * 4 + e;
    u32x4 o1;
    o1[0] = pk2(r1[0][e], r1[1][e]); o1[1] = pk2(r1[2][e], r1[3][e]);
    o1[2] = pk2(r1[4][e], r1[5][e]); o1[3] = pk2(r1[6][e], r1[7][e]);
    uint8_t* plane = dst + ((size_t)((kq * 8 + rw) * 64 + h)) * 1024;
    *(u32x4*)(plane + ra * 16) = o1;
  }
#pragma unroll
  for (int e = 0; e < 4; ++e) {  // window-2 stores
    const int h = hq * 4 + e;
    u32x4 o2;
    o2[0] = pk2(r2[0][e], r2[1][e]); o2[1] = pk2(r2[2][e], r2[3][e]);
    o2[2] = pk2(r2[4][e], r2[5][e]); o2[3] = pk2(r2[6][e], r2[7][e]);
    uint8_t* plane = dst + ((size_t)((kq * 8 + rw) * 64 + h)) * 1024;
    *(u32x4*)(plane + (ra + 32) * 16) = o2;
  }
}

// ---------- Pass 2: C[i,j,h] = (1/1024) sum_s A''[.,h,i]*B''[.,h,j]
// tile 128i x 128j x 4h, 512 thr (8 waves: hl = w&3, half = w>>2), BK=32.
// Reg-staged SINGLE 64KB LDS buffer (T14): issue next tile's 8 dwordx4 into regs
// before the MFMA phase, ds_write after the post-compute barrier -> load/compute
// overlap retained AND 2 blocks/CU (vs 128KB dbuf = 1 block/CU).
// XCD map x = (ip-pair, jt-pair, h-half): A/B re-reads XCD-local, C-line hg-siblings
// co-XCD (write merge). FETCH pinned at compulsory with this map (R8/R10).
__global__ __launch_bounds__(512, 4) void gemm_kernel(const uint8_t* __restrict__ ws,
                                                      float* __restrict__ Og) {
  __shared__ alignas(16) uint8_t lds[65536];  // A 32KB + B 32KB (epilogue image reuse)

  const int bid = blockIdx.x;
  const int x   = bid & 7;
  const int r   = bid >> 3;                             // 0..31
  const int ip  = (x >> 2) * 2 + (r & 1);               // i-panel 0..3
  const int jt  = ((x >> 1) & 1) * 2 + ((r >> 1) & 1);  // j-panel 0..3
  const int hg  = (x & 1) * 8 + (r >> 2);               // 0..15
  const int i0  = ip * 128;
  const int j0  = jt * 128;
  const int hg4 = hg * 4;

  const int t = threadIdx.x, lane = t & 63, w = t >> 6;
  const int hl = w & 3, half = w >> 2;
  const int frl = lane & 15, frg = lane >> 4;

  const uint8_t* Apk = ws;
  const uint8_t* Bpk = ws + WS_B_OFF;

  fragc acc[4][8];
#pragma unroll
  for (int m = 0; m < 4; ++m)
#pragma unroll
    for (int n = 0; n < 8; ++n)
      acc[m][n] = (fragc)0.0f;

  f32x4 sa[4], sb[4];

  // ws byte: ((kq*8 + chunk)*64 + h)*1024 + r64*16 ; each load = 16B of a 1KB plane slice.
#define LOADR(kt)                                                                   \
  {                                                                                 \
    _Pragma("unroll") for (int k2 = 0; k2 < 2; ++k2) {                              \
      const int ko = half * 2 + k2;                                                 \
      _Pragma("unroll") for (int p = 0; p < 2; ++p) {                               \
        const size_t pa =                                                           \
            ((size_t)(((kt) * 4 + ko) * 8 + (i0 >> 6) + p) * 64 + hg4 + hl) * 1024; \
        const size_t pb =                                                           \
            ((size_t)(((kt) * 4 + ko) * 8 + (j0 >> 6) + p) * 64 + hg4 + hl) * 1024; \
        sa[k2 * 2 + p] = *(const f32x4*)(Apk + pa + lane * 16);                     \
        sb[k2 * 2 + p] = *(const f32x4*)(Bpk + pb + lane * 16);                     \
      }                                                                             \
    }                                                                               \
  }

#define WSTAGE()                                                                    \
  {                                                                                 \
    _Pragma("unroll") for (int k2 = 0; k2 < 2; ++k2) {                              \
      const int ko = half * 2 + k2;                                                 \
      _Pragma("unroll") for (int p = 0; p < 2; ++p) {                               \
        const int lo = hl * 8192 + ko * 2048 + p * 1024 + lane * 16;                \
        *(f32x4*)(lds + lo) = sa[k2 * 2 + p];                                       \
        *(f32x4*)(lds + 32768 + lo) = sb[k2 * 2 + p];                               \
      }                                                                             \
    }                                                                               \
  }

  LOADR(0)
  WSTAGE()
  __syncthreads();  // tile 0 resident

  for (int kt = 0; kt < 32; ++kt) {
    if (kt < 31) LOADR(kt + 1)  // in flight across the MFMA phase
    {
      const uint8_t* La = lds + hl * 8192;
      const uint8_t* Lb = La + 32768;
      bf16x8 fb[8];
#pragma unroll
      for (int n = 0; n < 8; ++n)
        fb[n] = *(const bf16x8*)(Lb + frg * 2048 + (n * 16 + frl) * 16);
#pragma unroll
      for (int m = 0; m < 4; ++m) {
        bf16x8 fa = *(const bf16x8*)(La + frg * 2048 + (half * 64 + m * 16 + frl) * 16);
#pragma unroll
        for (int n = 0; n < 8; ++n)
          acc[m][n] = __builtin_amdgcn_mfma_f32_16x16x32_bf16(fa, fb[n], acc[m][n], 0, 0, 0);
      }
    }
    __syncthreads();  // all readers done with tile kt
    if (kt < 31) {
      WSTAGE()        // waits vmcnt for sa/sb (landed during MFMA phase)
      __syncthreads();  // tile kt+1 resident
    }
  }
#undef LOADR
#undef WSTAGE

  // epilogue: bounce C through LDS -> 16B/lane CACHED stores (L2 merges hg-sibling
  // lines; NT stores would 4x write traffic — R7 lesson).
  // chunk = 32 i-rows: LDS image [32 i][128 j][4 h] f32 = 64KB, addr-XOR swizzled.
  const float scale = 1.0f / 1024.0f;
  const int i_r = t >> 4, jo = t & 15;
#pragma unroll
  for (int cb = 0; cb < 4; ++cb) {
    __syncthreads();  // chunk cb-1 readers done / K-loop readers done
    if (half == (cb >> 1)) {
#pragma unroll
      for (int m2 = 0; m2 < 2; ++m2) {
        const int m = (cb & 1) * 2 + m2;
#pragma unroll
        for (int n = 0; n < 8; ++n) {
#pragma unroll
          for (int q = 0; q < 4; ++q) {
            const int il = m2 * 16 + frg * 4 + q;   // 0..31
            const int j  = n * 16 + frl;
            int byte = (il * 128 + j) * 16 + hl * 4;
            byte ^= ((byte >> 7) & 7) << 4;
            *(float*)(lds + byte) = acc[m][n][q] * scale;
          }
        }
      }
    }
    __syncthreads();  // chunk image ready
#pragma unroll
    for (int c = 0; c < 8; ++c) {
      int byte = (i_r * 128 + jo * 8 + c) * 16;
      byte ^= ((byte >> 7) & 7) << 4;
      const f32x4 v = *(const f32x4*)(lds + byte);
      *(f32x4*)(Og + ((size_t)(i0 + cb * 32 + i_r) * 512 + (j0 + jo * 8 + c)) * 64 + hg4) = v;
    }
  }
}

extern "C" void kernel_launch(void* const* d_in, const int* in_sizes, int n_in,
                              void* d_out, int out_size, void* d_ws, size_t ws_size,
                              hipStream_t stream) {
  const float* a = (const float*)d_in[0];
  const float* b = (const float*)d_in[1];
  float* out = (float*)d_out;
  uint8_t* ws = (uint8_t*)d_ws;
  pack_kernel<<<2048, 512, 0, stream>>>(a, b, ws);
  gemm_kernel<<<256, 512, 0, stream>>>(ws, out);
}

// Round 12
// 148.553 us; speedup vs baseline: 2.6520x; 2.6520x over previous
//
#include <hip/hip_runtime.h>
#include <stdint.h>

typedef float f32x4 __attribute__((ext_vector_type(4)));
typedef float f32x2 __attribute__((ext_vector_type(2)));
typedef short bf16x8 __attribute__((ext_vector_type(8)));
typedef float fragc __attribute__((ext_vector_type(4)));
typedef uint32_t u32x4 __attribute__((ext_vector_type(4)));

__device__ __forceinline__ uint32_t pk2(float lo, float hi) {
  // (bf16(lo) | bf16(hi)<<16) via one v_perm_b32 (truncating)
  return __builtin_amdgcn_perm(__float_as_uint(hi), __float_as_uint(lo), 0x07060302u);
}

__device__ __forceinline__ void gload16(const void* g, void* l) {
  __builtin_amdgcn_global_load_lds((const __attribute__((address_space(1))) uint32_t*)g,
                                   (__attribute__((address_space(3))) uint32_t*)l, 16, 0, 0);
}

#define WS_B_OFF 67108864ull  // B'' at ws + 64 MiB

// ---------- Pass 1 (at BW floor): [1024 s][512 r][64 h] f32
//   -> bf16 ws[kq 128][rw 8][h 64][r 64][16B]
// No LDS: lanes {c, c+16, c+32, c+48} of one store-instr write r=0..3 of the SAME
// 64B line (line-complete). Reads 1KB contiguous per wave-instr, NT (single-touch).
__global__ __launch_bounds__(512) void pack_kernel(const float* __restrict__ Ag,
                                                   const float* __restrict__ Bg,
                                                   uint8_t* __restrict__ ws) {
  const int bid  = blockIdx.x;
  const int rw   = bid & 7;
  const int kq   = (bid >> 3) & 127;
  const int side = bid >> 10;
  const int t    = threadIdx.x;

  const f32x4* S4 = (const f32x4*)(side ? Bg : Ag);
  uint8_t* dst = ws + (side ? WS_B_OFF : 0ull);

  const int base = rw * 1024 + t;
  f32x4 r1[8], r2[8];
#pragma unroll
  for (int e = 0; e < 8; ++e)
    r1[e] = __builtin_nontemporal_load(&S4[(size_t)(kq * 8 + e) * 8192 + base]);
#pragma unroll
  for (int e = 0; e < 8; ++e)
    r2[e] = __builtin_nontemporal_load(&S4[(size_t)(kq * 8 + e) * 8192 + base + 512]);

  const int hq = t & 15;
  const int ra = t >> 4;  // 0..31
#pragma unroll
  for (int e = 0; e < 4; ++e) {  // window-1 stores need only r1 (start at vmcnt(8))
    const int h = hq * 4 + e;
    u32x4 o1;
    o1[0] = pk2(r1[0][e], r1[1][e]); o1[1] = pk2(r1[2][e], r1[3][e]);
    o1[2] = pk2(r1[4][e], r1[5][e]); o1[3] = pk2(r1[6][e], r1[7][e]);
    uint8_t* plane = dst + ((size_t)((kq * 8 + rw) * 64 + h)) * 1024;
    *(u32x4*)(plane + ra * 16) = o1;
  }
#pragma unroll
  for (int e = 0; e < 4; ++e) {
    const int h = hq * 4 + e;
    u32x4 o2;
    o2[0] = pk2(r2[0][e], r2[1][e]); o2[1] = pk2(r2[2][e], r2[3][e]);
    o2[2] = pk2(r2[4][e], r2[5][e]); o2[3] = pk2(r2[6][e], r2[7][e]);
    uint8_t* plane = dst + ((size_t)((kq * 8 + rw) * 64 + h)) * 1024;
    *(u32x4*)(plane + (ra + 32) * 16) = o2;
  }
}

// ---------- Pass 2: C[i,j,h] = (1/1024) sum_s A''[.,h,i]*B''[.,h,j]
// tile 128i x 128j x 2h, 512 thr (8 waves: hl = w&1, half = (w>>1)&1, qj = w>>2),
// BK=32, gload_lds dbuf 2 x 32KB = 64KB -> 2 blocks/CU (TLP covers barrier drains;
// R10's 128KB dbuf was 1 block/CU, MfmaUtil 12%).
// XCD map x = (ip-pair, jt-pair, h-half): A/B re-reads XCD-local (R9's 2h attempt
// broke exactly this -> FETCH doubled), C-line hg2-siblings (0..7 <-> one 64B line)
// co-XCD. Per-XCD L2 per kt ~2MB < 4MB. grid 512 = 2/CU, all co-resident.
__global__ __launch_bounds__(512, 4) void gemm_kernel(const uint8_t* __restrict__ ws,
                                                      float* __restrict__ Og) {
  __shared__ alignas(16) uint8_t lds[65536];  // 2 x (A 16KB + B 16KB); epilogue image reuse

  const int bid = blockIdx.x;
  const int x   = bid & 7;            // XCD
  const int r   = bid >> 3;           // 0..63
  const int ipp = x >> 2, jtp = (x >> 1) & 1, hh = x & 1;
  const int ip  = ipp * 2 + (r >> 5);         // 0..3
  const int jt  = jtp * 2 + ((r >> 4) & 1);   // 0..3
  const int hg2 = hh * 16 + (r & 15);         // 0..31
  const int i0  = ip * 128;
  const int j0  = jt * 128;
  const int h0  = hg2 * 2;

  const int t = threadIdx.x, lane = t & 63, w = t >> 6;
  const int hl = w & 1, half = (w >> 1) & 1, qj = w >> 2;  // qj 0..1
  const int frl = lane & 15, frg = lane >> 4;

  const uint8_t* Apk = ws;
  const uint8_t* Bpk = ws + WS_B_OFF;

  fragc acc[4][4];
#pragma unroll
  for (int m = 0; m < 4; ++m)
#pragma unroll
    for (int n = 0; n < 4; ++n)
      acc[m][n] = (fragc)0.0f;

  // staging: 32KB/tile over 512 thr = 2 A-gloads + 2 B-gloads per thread.
  // seg sg = (shl*8 + sko*2 + sp); wave w owns segs {2w, 2w+1} for A and B.
  // ws byte: ((kq*8 + chunk)*64 + h)*1024 + r64*16
#define ISSUE(kt, b)                                                               \
  {                                                                                \
    _Pragma("unroll") for (int u = 0; u < 2; ++u) {                                \
      const int sg  = w * 2 + u;                                                   \
      const int shl = sg >> 3, sko = (sg >> 1) & 3, sp = sg & 1;                   \
      const size_t pa =                                                            \
          ((size_t)(((kt) * 4 + sko) * 8 + (i0 >> 6) + sp) * 64 + h0 + shl);       \
      const size_t pb =                                                            \
          ((size_t)(((kt) * 4 + sko) * 8 + (j0 >> 6) + sp) * 64 + h0 + shl);       \
      gload16(Apk + pa * 1024 + lane * 16, lds + (b) * 32768 + sg * 1024 + lane * 16); \
      gload16(Bpk + pb * 1024 + lane * 16,                                         \
              lds + (b) * 32768 + 16384 + sg * 1024 + lane * 16);                  \
    }                                                                              \
  }

  ISSUE(0, 0)

  for (int kt = 0; kt < 32; ++kt) {
    __syncthreads();  // drains gloads of tile kt; joins readers of buf b^1
    const int b = kt & 1;
    if (kt < 31) ISSUE(kt + 1, b ^ 1)
    const uint8_t* bufp = lds + b * 32768;
    // frag segs: (hl, ko=frg, p=half/qj)
    const uint8_t* La = bufp + (hl * 8 + frg * 2 + half) * 1024;
    const uint8_t* Lb = bufp + 16384 + (hl * 8 + frg * 2 + qj) * 1024;
    bf16x8 fb[4];
#pragma unroll
    for (int n = 0; n < 4; ++n)
      fb[n] = *(const bf16x8*)(Lb + (n * 16 + frl) * 16);
#pragma unroll
    for (int m = 0; m < 4; ++m) {
      bf16x8 fa = *(const bf16x8*)(La + (m * 16 + frl) * 16);
#pragma unroll
      for (int n = 0; n < 4; ++n)
        acc[m][n] = __builtin_amdgcn_mfma_f32_16x16x32_bf16(fa, fb[n], acc[m][n], 0, 0, 0);
    }
  }
#undef ISSUE

  // epilogue: bounce C through a 32KB LDS image [32 il][128 j][2 h] f32 (byte-swizzled
  // ^=(il&7)<<4), then 8B/lane cached stores; L2 merges the 8 co-XCD hg2-siblings
  // of each 64B C-line (NT stores would 4x write traffic — R7 lesson).
  const float scale = 1.0f / 1024.0f;
  const int i_r = t >> 4, jo = t & 15;
#pragma unroll
  for (int cb = 0; cb < 4; ++cb) {
    __syncthreads();  // chunk cb-1 readers done / K-loop readers done
    if (half == (cb >> 1)) {
#pragma unroll
      for (int m2 = 0; m2 < 2; ++m2) {
        const int m = (cb & 1) * 2 + m2;
#pragma unroll
        for (int n = 0; n < 4; ++n) {
#pragma unroll
          for (int q = 0; q < 4; ++q) {
            const int il = m2 * 16 + frg * 4 + q;   // 0..31
            const int j  = qj * 64 + n * 16 + frl;  // 0..127
            const int byte = (il * 1024 + j * 8 + hl * 4) ^ ((il & 7) << 4);
            *(float*)(lds + byte) = acc[m][n][q] * scale;
          }
        }
      }
    }
    __syncthreads();  // chunk image ready
#pragma unroll
    for (int c = 0; c < 8; ++c) {
      const int byte = (i_r * 1024 + (jo * 8 + c) * 8) ^ ((i_r & 7) << 4);
      const f32x2 v = *(const f32x2*)(lds + byte);
      *(f32x2*)(Og + ((size_t)(i0 + cb * 32 + i_r) * 512 + (j0 + jo * 8 + c)) * 64 + h0) = v;
    }
  }
}

extern "C" void kernel_launch(void* const* d_in, const int* in_sizes, int n_in,
                              void* d_out, int out_size, void* d_ws, size_t ws_size,
                              hipStream_t stream) {
  const float* a = (const float*)d_in[0];
  const float* b = (const float*)d_in[1];
  float* out = (float*)d_out;
  uint8_t* ws = (uint8_t*)d_ws;
  pack_kernel<<<2048, 512, 0, stream>>>(a, b, ws);
  gemm_kernel<<<512, 512, 0, stream>>>(ws, out);
}

// Round 13
// 133.131 us; speedup vs baseline: 2.9592x; 1.1158x over previous
//
#include <hip/hip_runtime.h>
#include <stdint.h>

typedef float f32x4 __attribute__((ext_vector_type(4)));
typedef short bf16x8 __attribute__((ext_vector_type(8)));
typedef float fragc __attribute__((ext_vector_type(4)));
typedef uint32_t u32x4 __attribute__((ext_vector_type(4)));

__device__ __forceinline__ uint32_t pk2(float lo, float hi) {
  // (bf16(lo) | bf16(hi)<<16) via one v_perm_b32 (truncating)
  return __builtin_amdgcn_perm(__float_as_uint(hi), __float_as_uint(lo), 0x07060302u);
}

__device__ __forceinline__ void gload16(const void* g, void* l) {
  __builtin_amdgcn_global_load_lds((const __attribute__((address_space(1))) uint32_t*)g,
                                   (__attribute__((address_space(3))) uint32_t*)l, 16, 0, 0);
}

#define WS_B_OFF 67108864ull  // B'' at ws + 64 MiB

// ---------- Pass 1 (R12 version — at HW floor ~55us): [1024 s][512 r][64 h] f32
//   -> bf16 ws[kq 128][rw 8][h 64][r 64][16B]
// No LDS: lanes {c, c+16, c+32, c+48} of one store-instr write r=0..3 of the SAME
// 64B line (line-complete). Reads 1KB contiguous per wave-instr, NT (single-touch).
// Window-split load/store order lets stores start at vmcnt(8).
__global__ __launch_bounds__(512) void pack_kernel(const float* __restrict__ Ag,
                                                   const float* __restrict__ Bg,
                                                   uint8_t* __restrict__ ws) {
  const int bid  = blockIdx.x;
  const int rw   = bid & 7;
  const int kq   = (bid >> 3) & 127;
  const int side = bid >> 10;
  const int t    = threadIdx.x;

  const f32x4* S4 = (const f32x4*)(side ? Bg : Ag);
  uint8_t* dst = ws + (side ? WS_B_OFF : 0ull);

  const int base = rw * 1024 + t;
  f32x4 r1[8], r2[8];
#pragma unroll
  for (int e = 0; e < 8; ++e)
    r1[e] = __builtin_nontemporal_load(&S4[(size_t)(kq * 8 + e) * 8192 + base]);
#pragma unroll
  for (int e = 0; e < 8; ++e)
    r2[e] = __builtin_nontemporal_load(&S4[(size_t)(kq * 8 + e) * 8192 + base + 512]);

  const int hq = t & 15;
  const int ra = t >> 4;  // 0..31
#pragma unroll
  for (int e = 0; e < 4; ++e) {  // window-1 stores need only r1 (start at vmcnt(8))
    const int h = hq * 4 + e;
    u32x4 o1;
    o1[0] = pk2(r1[0][e], r1[1][e]); o1[1] = pk2(r1[2][e], r1[3][e]);
    o1[2] = pk2(r1[4][e], r1[5][e]); o1[3] = pk2(r1[6][e], r1[7][e]);
    uint8_t* plane = dst + ((size_t)((kq * 8 + rw) * 64 + h)) * 1024;
    *(u32x4*)(plane + ra * 16) = o1;
  }
#pragma unroll
  for (int e = 0; e < 4; ++e) {
    const int h = hq * 4 + e;
    u32x4 o2;
    o2[0] = pk2(r2[0][e], r2[1][e]); o2[1] = pk2(r2[2][e], r2[3][e]);
    o2[2] = pk2(r2[4][e], r2[5][e]); o2[3] = pk2(r2[6][e], r2[7][e]);
    uint8_t* plane = dst + ((size_t)((kq * 8 + rw) * 64 + h)) * 1024;
    *(u32x4*)(plane + (ra + 32) * 16) = o2;
  }
}

// ---------- Pass 2 (R10 version — measured ~53us): C[i,j,h] = (1/1024) sum_s A''*B''
// tile 128i x 128j x 4h, 512 thr (8 waves: hl = w&3, half = w>>2), BK=32, dbuf 128KB.
// Fat 4h phase: 32 MFMA per wave-phase over 12 ds_read_b128 (frag reuse) — R12 showed
// thin 2h phases regress 1.7x despite 2 blocks/CU; phase depth > occupancy here.
// XCD map x = (ip-pair, jt-pair, h-half): A/B re-reads XCD-local, C-line hg-siblings
// co-XCD (write merge). FETCH pinned at compulsory with this map (R8/R10/R12).
__global__ __launch_bounds__(512, 2) void gemm_kernel(const uint8_t* __restrict__ ws,
                                                      float* __restrict__ Og) {
  __shared__ alignas(16) uint8_t lds[131072];  // 2 x (A 32KB + B 32KB)

  const int bid = blockIdx.x;
  const int x   = bid & 7;
  const int r   = bid >> 3;                             // 0..31
  const int ip  = (x >> 2) * 2 + (r & 1);               // i-panel 0..3
  const int jt  = ((x >> 1) & 1) * 2 + ((r >> 1) & 1);  // j-panel 0..3
  const int hg  = (x & 1) * 8 + (r >> 2);               // 0..15
  const int i0  = ip * 128;
  const int j0  = jt * 128;
  const int hg4 = hg * 4;

  const int t = threadIdx.x, lane = t & 63, w = t >> 6;
  const int hl = w & 3, half = w >> 2;
  const int frl = lane & 15, frg = lane >> 4;

  const uint8_t* Apk = ws;
  const uint8_t* Bpk = ws + WS_B_OFF;

  fragc acc[4][8];
#pragma unroll
  for (int m = 0; m < 4; ++m)
#pragma unroll
    for (int n = 0; n < 8; ++n)
      acc[m][n] = (fragc)0.0f;

  // staging: wave (hl, half) loads ko-planes {2*half, 2*half+1} of its h, A and B.
  // ws byte: ((kq*8 + chunk)*64 + h)*1024 + r64*16 ; each gload = 1KB plane slice.
#define ISSUE(kt, b)                                                                \
  {                                                                                 \
    _Pragma("unroll") for (int k2 = 0; k2 < 2; ++k2) {                              \
      const int ko = half * 2 + k2;                                                 \
      _Pragma("unroll") for (int p = 0; p < 2; ++p) {                               \
        const size_t pa =                                                           \
            ((size_t)(((kt) * 4 + ko) * 8 + (i0 >> 6) + p) * 64 + hg4 + hl) * 1024; \
        const size_t pb =                                                           \
            ((size_t)(((kt) * 4 + ko) * 8 + (j0 >> 6) + p) * 64 + hg4 + hl) * 1024; \
        gload16(Apk + pa + lane * 16,                                               \
                lds + (b) * 65536 + hl * 8192 + ko * 2048 + p * 1024);              \
        gload16(Bpk + pb + lane * 16,                                               \
                lds + (b) * 65536 + 32768 + hl * 8192 + ko * 2048 + p * 1024);      \
      }                                                                             \
    }                                                                               \
  }

  ISSUE(0, 0)

  for (int kt = 0; kt < 32; ++kt) {
    __syncthreads();  // drains gloads of tile kt; joins readers of buf b^1
    const int b = kt & 1;
    if (kt < 31) ISSUE(kt + 1, b ^ 1)
    const uint8_t* La = lds + b * 65536 + hl * 8192;
    const uint8_t* Lb = La + 32768;
    bf16x8 fb[8];
#pragma unroll
    for (int n = 0; n < 8; ++n)
      fb[n] = *(const bf16x8*)(Lb + frg * 2048 + (n * 16 + frl) * 16);
#pragma unroll
    for (int m = 0; m < 4; ++m) {
      bf16x8 fa = *(const bf16x8*)(La + frg * 2048 + (half * 64 + m * 16 + frl) * 16);
#pragma unroll
      for (int n = 0; n < 8; ++n)
        acc[m][n] = __builtin_amdgcn_mfma_f32_16x16x32_bf16(fa, fb[n], acc[m][n], 0, 0, 0);
    }
  }
#undef ISSUE

  // epilogue: bounce C through LDS -> 16B/lane CACHED stores (L2 merges hg-sibling
  // lines; NT stores would 4x write traffic — R7 lesson).
  const float scale = 1.0f / 1024.0f;
  const int i_r = t >> 4, jo = t & 15;
#pragma unroll
  for (int cb = 0; cb < 4; ++cb) {
    __syncthreads();  // chunk cb-1 readers done / K-loop readers done
    if (half == (cb >> 1)) {
#pragma unroll
      for (int m2 = 0; m2 < 2; ++m2) {
        const int m = (cb & 1) * 2 + m2;
#pragma unroll
        for (int n = 0; n < 8; ++n) {
#pragma unroll
          for (int q = 0; q < 4; ++q) {
            const int il = m2 * 16 + frg * 4 + q;   // 0..31
            const int j  = n * 16 + frl;
            int byte = (il * 128 + j) * 16 + hl * 4;
            byte ^= ((byte >> 7) & 7) << 4;
            *(float*)(lds + byte) = acc[m][n][q] * scale;
          }
        }
      }
    }
    __syncthreads();  // chunk image ready
#pragma unroll
    for (int c = 0; c < 8; ++c) {
      int byte = (i_r * 128 + jo * 8 + c) * 16;
      byte ^= ((byte >> 7) & 7) << 4;
      const f32x4 v = *(const f32x4*)(lds + byte);
      *(f32x4*)(Og + ((size_t)(i0 + cb * 32 + i_r) * 512 + (j0 + jo * 8 + c)) * 64 + hg4) = v;
    }
  }
}

extern "C" void kernel_launch(void* const* d_in, const int* in_sizes, int n_in,
                              void* d_out, int out_size, void* d_ws, size_t ws_size,
                              hipStream_t stream) {
  const float* a = (const float*)d_in[0];
  const float* b = (const float*)d_in[1];
  float* out = (float*)d_out;
  uint8_t* ws = (uint8_t*)d_ws;
  pack_kernel<<<2048, 512, 0, stream>>>(a, b, ws);
  gemm_kernel<<<256, 512, 0, stream>>>(ws, out);
}

// Round 14
// 130.950 us; speedup vs baseline: 3.0085x; 1.0167x over previous
//
#include <hip/hip_runtime.h>
#include <stdint.h>

typedef float f32x4 __attribute__((ext_vector_type(4)));
typedef short bf16x8 __attribute__((ext_vector_type(8)));
typedef float fragc __attribute__((ext_vector_type(4)));
typedef uint32_t u32x4 __attribute__((ext_vector_type(4)));

__device__ __forceinline__ uint32_t pk2(float lo, float hi) {
  // (bf16(lo) | bf16(hi)<<16) via one v_perm_b32 (truncating)
  return __builtin_amdgcn_perm(__float_as_uint(hi), __float_as_uint(lo), 0x07060302u);
}

__device__ __forceinline__ void gload16(const void* g, void* l) {
  __builtin_amdgcn_global_load_lds((const __attribute__((address_space(1))) uint32_t*)g,
                                   (__attribute__((address_space(3))) uint32_t*)l, 16, 0, 0);
}

#define WS_B_OFF 67108864ull  // B'' at ws + 64 MiB

// ---------- Pass 1 (at ~86% of mixed-stream HW floor): [1024 s][512 r][64 h] f32
//   -> bf16 ws[kq 128][rw 8][h 64][r 64][16B]
// No LDS: lanes {c, c+16, c+32, c+48} of one store-instr write r=0..3 of the SAME
// 64B line (line-complete). Reads 1KB contiguous per wave-instr, NT (single-touch).
// Window-split load/store order lets stores start at vmcnt(8).
__global__ __launch_bounds__(512) void pack_kernel(const float* __restrict__ Ag,
                                                   const float* __restrict__ Bg,
                                                   uint8_t* __restrict__ ws) {
  const int bid  = blockIdx.x;
  const int rw   = bid & 7;
  const int kq   = (bid >> 3) & 127;
  const int side = bid >> 10;
  const int t    = threadIdx.x;

  const f32x4* S4 = (const f32x4*)(side ? Bg : Ag);
  uint8_t* dst = ws + (side ? WS_B_OFF : 0ull);

  const int base = rw * 1024 + t;
  f32x4 r1[8], r2[8];
#pragma unroll
  for (int e = 0; e < 8; ++e)
    r1[e] = __builtin_nontemporal_load(&S4[(size_t)(kq * 8 + e) * 8192 + base]);
#pragma unroll
  for (int e = 0; e < 8; ++e)
    r2[e] = __builtin_nontemporal_load(&S4[(size_t)(kq * 8 + e) * 8192 + base + 512]);

  const int hq = t & 15;
  const int ra = t >> 4;  // 0..31
#pragma unroll
  for (int e = 0; e < 4; ++e) {  // window-1 stores need only r1 (start at vmcnt(8))
    const int h = hq * 4 + e;
    u32x4 o1;
    o1[0] = pk2(r1[0][e], r1[1][e]); o1[1] = pk2(r1[2][e], r1[3][e]);
    o1[2] = pk2(r1[4][e], r1[5][e]); o1[3] = pk2(r1[6][e], r1[7][e]);
    uint8_t* plane = dst + ((size_t)((kq * 8 + rw) * 64 + h)) * 1024;
    *(u32x4*)(plane + ra * 16) = o1;
  }
#pragma unroll
  for (int e = 0; e < 4; ++e) {
    const int h = hq * 4 + e;
    u32x4 o2;
    o2[0] = pk2(r2[0][e], r2[1][e]); o2[1] = pk2(r2[2][e], r2[3][e]);
    o2[2] = pk2(r2[4][e], r2[5][e]); o2[3] = pk2(r2[6][e], r2[7][e]);
    uint8_t* plane = dst + ((size_t)((kq * 8 + rw) * 64 + h)) * 1024;
    *(u32x4*)(plane + (ra + 32) * 16) = o2;
  }
}

// ---------- Pass 2: C[i,j,h] = (1/1024) sum_s A''*B''
// tile 128i x 128j x 4h, 512 thr (8 waves: hl = w&3, half = w>>2), BK=32, dbuf 128KB.
// T4 counted-vmcnt pipeline: raw s_barrier + per-wave "s_waitcnt vmcnt(8)" keeps the
// 8 gloads of tile kt+1 IN FLIGHT across the barrier (a __syncthreads would drain
// vmcnt to 0 every kt -> the R10-R13 ~13% MfmaUtil plateau).
// XCD map x = (ip-pair, jt-pair, h-half): A/B re-reads XCD-local, C-line hg-siblings
// co-XCD (write merge). FETCH pinned at compulsory with this map (R8/R10/R12/R13).
__global__ __launch_bounds__(512, 2) void gemm_kernel(const uint8_t* __restrict__ ws,
                                                      float* __restrict__ Og) {
  __shared__ alignas(16) uint8_t lds[131072];  // 2 x (A 32KB + B 32KB)

  const int bid = blockIdx.x;
  const int x   = bid & 7;
  const int r   = bid >> 3;                             // 0..31
  const int ip  = (x >> 2) * 2 + (r & 1);               // i-panel 0..3
  const int jt  = ((x >> 1) & 1) * 2 + ((r >> 1) & 1);  // j-panel 0..3
  const int hg  = (x & 1) * 8 + (r >> 2);               // 0..15
  const int i0  = ip * 128;
  const int j0  = jt * 128;
  const int hg4 = hg * 4;

  const int t = threadIdx.x, lane = t & 63, w = t >> 6;
  const int hl = w & 3, half = w >> 2;
  const int frl = lane & 15, frg = lane >> 4;

  const uint8_t* Apk = ws;
  const uint8_t* Bpk = ws + WS_B_OFF;

  fragc acc[4][8];
#pragma unroll
  for (int m = 0; m < 4; ++m)
#pragma unroll
    for (int n = 0; n < 8; ++n)
      acc[m][n] = (fragc)0.0f;

  // staging: wave (hl, half) loads ko-planes {2*half, 2*half+1} of its h, A and B.
  // ws byte: ((kq*8 + chunk)*64 + h)*1024 + r64*16 ; 8 gload16 per thread = 8/wave.
#define ISSUE(kt, b)                                                                \
  {                                                                                 \
    _Pragma("unroll") for (int k2 = 0; k2 < 2; ++k2) {                              \
      const int ko = half * 2 + k2;                                                 \
      _Pragma("unroll") for (int p = 0; p < 2; ++p) {                               \
        const size_t pa =                                                           \
            ((size_t)(((kt) * 4 + ko) * 8 + (i0 >> 6) + p) * 64 + hg4 + hl) * 1024; \
        const size_t pb =                                                           \
            ((size_t)(((kt) * 4 + ko) * 8 + (j0 >> 6) + p) * 64 + hg4 + hl) * 1024; \
        gload16(Apk + pa + lane * 16,                                               \
                lds + (b) * 65536 + hl * 8192 + ko * 2048 + p * 1024);              \
        gload16(Bpk + pb + lane * 16,                                               \
                lds + (b) * 65536 + 32768 + hl * 8192 + ko * 2048 + p * 1024);      \
      }                                                                             \
    }                                                                               \
  }

  ISSUE(0, 0)

  for (int kt = 0; kt < 32; ++kt) {
    const int b = kt & 1;
    if (kt < 31) {
      ISSUE(kt + 1, b ^ 1)  // 8 gloads/wave for the next tile, kept in flight
      asm volatile("s_waitcnt vmcnt(8)" ::: "memory");  // own tile-kt loads done
    } else {
      asm volatile("s_waitcnt vmcnt(0)" ::: "memory");
    }
    __builtin_amdgcn_s_barrier();        // all waves' tile-kt loads done
    asm volatile("" ::: "memory");       // pin ds_reads below the barrier
    {
      const uint8_t* La = lds + b * 65536 + hl * 8192;
      const uint8_t* Lb = La + 32768;
      bf16x8 fb[8];
#pragma unroll
      for (int n = 0; n < 8; ++n)
        fb[n] = *(const bf16x8*)(Lb + frg * 2048 + (n * 16 + frl) * 16);
#pragma unroll
      for (int m = 0; m < 4; ++m) {
        bf16x8 fa = *(const bf16x8*)(La + frg * 2048 + (half * 64 + m * 16 + frl) * 16);
#pragma unroll
        for (int n = 0; n < 8; ++n)
          acc[m][n] = __builtin_amdgcn_mfma_f32_16x16x32_bf16(fa, fb[n], acc[m][n], 0, 0, 0);
      }
    }
    asm volatile("" ::: "memory");       // pin ds_reads above the barrier
    __builtin_amdgcn_s_barrier();        // buf b free for ISSUE(kt+2) next iter
  }
#undef ISSUE

  // epilogue: bounce C through LDS -> 16B/lane CACHED stores (L2 merges hg-sibling
  // lines; NT stores would 4x write traffic — R7 lesson).
  const float scale = 1.0f / 1024.0f;
  const int i_r = t >> 4, jo = t & 15;
#pragma unroll
  for (int cb = 0; cb < 4; ++cb) {
    __syncthreads();  // chunk cb-1 readers done / K-loop readers done
    if (half == (cb >> 1)) {
#pragma unroll
      for (int m2 = 0; m2 < 2; ++m2) {
        const int m = (cb & 1) * 2 + m2;
#pragma unroll
        for (int n = 0; n < 8; ++n) {
#pragma unroll
          for (int q = 0; q < 4; ++q) {
            const int il = m2 * 16 + frg * 4 + q;   // 0..31
            const int j  = n * 16 + frl;
            int byte = (il * 128 + j) * 16 + hl * 4;
            byte ^= ((byte >> 7) & 7) << 4;
            *(float*)(lds + byte) = acc[m][n][q] * scale;
          }
        }
      }
    }
    __syncthreads();  // chunk image ready
#pragma unroll
    for (int c = 0; c < 8; ++c) {
      int byte = (i_r * 128 + jo * 8 + c) * 16;
      byte ^= ((byte >> 7) & 7) << 4;
      const f32x4 v = *(const f32x4*)(lds + byte);
      *(f32x4*)(Og + ((size_t)(i0 + cb * 32 + i_r) * 512 + (j0 + jo * 8 + c)) * 64 + hg4) = v;
    }
  }
}

extern "C" void kernel_launch(void* const* d_in, const int* in_sizes, int n_in,
                              void* d_out, int out_size, void* d_ws, size_t ws_size,
                              hipStream_t stream) {
  const float* a = (const float*)d_in[0];
  const float* b = (const float*)d_in[1];
  float* out = (float*)d_out;
  uint8_t* ws = (uint8_t*)d_ws;
  pack_kernel<<<2048, 512, 0, stream>>>(a, b, ws);
  gemm_kernel<<<256, 512, 0, stream>>>(ws, out);
}